// Round 1
// baseline (2224.484 us; speedup 1.0000x reference)
//
#include <hip/hip_runtime.h>
#include <math.h>

// ScaledDotProductAttention: B=4,H=16,S=2048,D=64, fp32 in, outputs (out, attn) fp32.
// out region: [0, B*H*S*D), attn region: [B*H*S*D, B*H*S*D + B*H*S*S).
//
// Design (round 1):
//  - 1 workgroup (256 thr = 4 waves) per (bh, 16-q-row stripe). 8192 wgs.
//  - QK^T via mfma_f32_16x16x32_bf16 with bf16x3 split (hi*hi + hi*lo + lo*hi)
//    for fp32-faithful logits. Scores (16x2048) held in C-fragments: 32 float4/lane.
//  - Exact softmax (row max over full row -> exp -> sum) via shfl_xor butterflies
//    (reduce over lane&15) + tiny LDS cross-wave combine.
//  - attn (normalized p, fp32) stored straight from C-layout registers.
//  - PV via bf16 mfma: p C-layout -> LDS -> A-layout; v transposed into LDS, in
//    8 chunks of 256 j to bound LDS (~43 KB -> 2 wg/CU).

#define SEQ 2048
#define HD 64
#define NH 16
#define NB 4

typedef float floatx4 __attribute__((ext_vector_type(4)));
typedef __bf16 bf16x8 __attribute__((ext_vector_type(8)));

__device__ __forceinline__ void split8(const float4 a, const float4 b, const float s,
                                       bf16x8& hi, bf16x8& lo) {
  float f[8] = {a.x * s, a.y * s, a.z * s, a.w * s,
                b.x * s, b.y * s, b.z * s, b.w * s};
#pragma unroll
  for (int j = 0; j < 8; ++j) {
    __bf16 h = (__bf16)f[j];
    hi[j] = h;
    lo[j] = (__bf16)(f[j] - (float)h);
  }
}

__global__ __launch_bounds__(256, 2) void sdpa_kernel(
    const float* __restrict__ qp, const float* __restrict__ kp,
    const float* __restrict__ vp, const int* __restrict__ maskp,
    float* __restrict__ outp) {
  const int tid  = threadIdx.x;
  const int lane = tid & 63;
  const int w    = tid >> 6;    // wave 0..3
  const int ll   = lane & 15;   // "n"/"m" lane within mfma
  const int quad = lane >> 4;   // 0..3
  const int q0   = blockIdx.x * 16;
  const int bh   = blockIdx.y;
  const int b    = bh >> 4;

  __shared__ __align__(16) __bf16 vT[64][264];   // v^T chunk: [d][j_local], pad 8
  __shared__ __align__(16) __bf16 pC[16][264];   // p chunk:   [q][j_local], pad 8
  __shared__ float red_m[4][16];
  __shared__ float red_l[4][16];

  const size_t bh_off = (size_t)bh * (SEQ * HD);

  // ---- q fragments (A-layout: m=ll holds q row q0+ll, k = quad*8+j (+32)) ----
  bf16x8 qhi0, qlo0, qhi1, qlo1;
  {
    const float* qr = qp + bh_off + (size_t)(q0 + ll) * HD + quad * 8;
    float4 a0 = *(const float4*)(qr);
    float4 a1 = *(const float4*)(qr + 4);
    float4 a2 = *(const float4*)(qr + 32);
    float4 a3 = *(const float4*)(qr + 36);
    split8(a0, a1, 0.125f, qhi0, qlo0);   // fold 1/TEMPERATURE into q
    split8(a2, a3, 0.125f, qhi1, qlo1);
  }

  // ---- QK^T: wave w owns tiles T = 4i+w (cols T*16..T*16+15), i=0..31 ----
  floatx4 acc[32];
#pragma unroll
  for (int i = 0; i < 32; ++i) acc[i] = 0.f;

  const float* kb = kp + bh_off;
#pragma unroll
  for (int i = 0; i < 32; ++i) {
    const int col0 = (4 * i + w) * 16;
    const float* kr = kb + (size_t)(col0 + ll) * HD + quad * 8;
    float4 a0 = *(const float4*)(kr);
    float4 a1 = *(const float4*)(kr + 4);
    float4 a2 = *(const float4*)(kr + 32);
    float4 a3 = *(const float4*)(kr + 36);
    bf16x8 khi0, klo0, khi1, klo1;
    split8(a0, a1, 1.f, khi0, klo0);
    split8(a2, a3, 1.f, khi1, klo1);
    floatx4 t = acc[i];
    t = __builtin_amdgcn_mfma_f32_16x16x32_bf16(qhi0, khi0, t, 0, 0, 0);
    t = __builtin_amdgcn_mfma_f32_16x16x32_bf16(qlo0, khi0, t, 0, 0, 0);
    t = __builtin_amdgcn_mfma_f32_16x16x32_bf16(qhi0, klo0, t, 0, 0, 0);
    t = __builtin_amdgcn_mfma_f32_16x16x32_bf16(qhi1, khi1, t, 0, 0, 0);
    t = __builtin_amdgcn_mfma_f32_16x16x32_bf16(qlo1, khi1, t, 0, 0, 0);
    t = __builtin_amdgcn_mfma_f32_16x16x32_bf16(qhi1, klo1, t, 0, 0, 0);
    acc[i] = t;
  }

  // ---- mask + row max (C-layout: score row = quad*4+r, col = tile*16+ll) ----
  const int* mb = maskp + (size_t)b * SEQ * SEQ;
  float mx[4] = {-INFINITY, -INFINITY, -INFINITY, -INFINITY};
#pragma unroll
  for (int i = 0; i < 32; ++i) {
    const int col = (4 * i + w) * 16 + ll;
#pragma unroll
    for (int r = 0; r < 4; ++r) {
      const int row = q0 + quad * 4 + r;
      const int mv = mb[(size_t)row * SEQ + col];
      float sv = mv ? -1e9f : acc[i][r];
      acc[i][r] = sv;
      mx[r] = fmaxf(mx[r], sv);
    }
  }
  // butterfly over the 16 "col" lanes (low 4 lane bits)
#pragma unroll
  for (int d = 1; d < 16; d <<= 1) {
#pragma unroll
    for (int r = 0; r < 4; ++r) mx[r] = fmaxf(mx[r], __shfl_xor(mx[r], d, 64));
  }
  if (ll == 0) {
#pragma unroll
    for (int r = 0; r < 4; ++r) red_m[w][quad * 4 + r] = mx[r];
  }
  __syncthreads();
  float mrow[4];
#pragma unroll
  for (int r = 0; r < 4; ++r) {
    const int row = quad * 4 + r;
    mrow[r] = fmaxf(fmaxf(red_m[0][row], red_m[1][row]),
                    fmaxf(red_m[2][row], red_m[3][row]));
  }

  // ---- exp + row sum ----
  float sm[4] = {0.f, 0.f, 0.f, 0.f};
#pragma unroll
  for (int i = 0; i < 32; ++i) {
#pragma unroll
    for (int r = 0; r < 4; ++r) {
      float e = __expf(acc[i][r] - mrow[r]);
      acc[i][r] = e;
      sm[r] += e;
    }
  }
#pragma unroll
  for (int d = 1; d < 16; d <<= 1) {
#pragma unroll
    for (int r = 0; r < 4; ++r) sm[r] += __shfl_xor(sm[r], d, 64);
  }
  if (ll == 0) {
#pragma unroll
    for (int r = 0; r < 4; ++r) red_l[w][quad * 4 + r] = sm[r];
  }
  __syncthreads();
  float linv[4];
#pragma unroll
  for (int r = 0; r < 4; ++r) {
    const int row = quad * 4 + r;
    linv[r] = 1.0f / (red_l[0][row] + red_l[1][row] + red_l[2][row] + red_l[3][row]);
  }

  // ---- normalize + store attn (fp32, straight from registers) ----
  float* attn = outp + (size_t)(NB * NH * SEQ * HD) + (size_t)bh * SEQ * SEQ;
#pragma unroll
  for (int i = 0; i < 32; ++i) {
    const int col = (4 * i + w) * 16 + ll;
#pragma unroll
    for (int r = 0; r < 4; ++r) {
      const int row = q0 + quad * 4 + r;
      float p = acc[i][r] * linv[r];
      acc[i][r] = p;
      attn[(size_t)row * SEQ + col] = p;
    }
  }

  // ---- PV: 8 chunks of 256 j; p via LDS (C->A layout), v transposed in LDS ----
  floatx4 oacc = 0.f;
  const float* vb = vp + bh_off;
#pragma unroll
  for (int c = 0; c < 8; ++c) {
    // stage v^T chunk: thread tid handles j = c*256+tid (bf16)
    {
      const float* vr = vb + (size_t)(c * 256 + tid) * HD;
#pragma unroll
      for (int d4 = 0; d4 < 16; ++d4) {
        float4 vv = *(const float4*)(vr + d4 * 4);
        vT[d4 * 4 + 0][tid] = (__bf16)vv.x;
        vT[d4 * 4 + 1][tid] = (__bf16)vv.y;
        vT[d4 * 4 + 2][tid] = (__bf16)vv.z;
        vT[d4 * 4 + 3][tid] = (__bf16)vv.w;
      }
    }
    // stage p chunk: wave w owns acc[4c+u], local tile lt = w+4u
#pragma unroll
    for (int u = 0; u < 4; ++u) {
      const int lt = w + 4 * u;
#pragma unroll
      for (int r = 0; r < 4; ++r)
        pC[quad * 4 + r][lt * 16 + ll] = (__bf16)acc[4 * c + u][r];
    }
    __syncthreads();
    // out tile: rows q0..q0+15, cols d = w*16..w*16+15; K-loop over chunk
#pragma unroll
    for (int kk = 0; kk < 8; ++kk) {
      bf16x8 af = *(const bf16x8*)&pC[ll][kk * 32 + quad * 8];
      bf16x8 bf = *(const bf16x8*)&vT[w * 16 + ll][kk * 32 + quad * 8];
      oacc = __builtin_amdgcn_mfma_f32_16x16x32_bf16(af, bf, oacc, 0, 0, 0);
    }
    __syncthreads();
  }

  // ---- store out (C-layout: row = quad*4+r, col = w*16+ll) ----
  float* ob = outp + bh_off + (size_t)q0 * HD;
#pragma unroll
  for (int r = 0; r < 4; ++r)
    ob[(size_t)(quad * 4 + r) * HD + w * 16 + ll] = oacc[r];
}

extern "C" void kernel_launch(void* const* d_in, const int* in_sizes, int n_in,
                              void* d_out, int out_size, void* d_ws, size_t ws_size,
                              hipStream_t stream) {
  const float* q = (const float*)d_in[0];
  const float* k = (const float*)d_in[1];
  const float* v = (const float*)d_in[2];
  const int* mask = (const int*)d_in[3];
  float* out = (float*)d_out;
  dim3 grid(SEQ / 16, NB * NH);
  sdpa_kernel<<<grid, dim3(256), 0, stream>>>(q, k, v, mask, out);
}